// Round 4
// baseline (9883.350 us; speedup 1.0000x reference)
//
#include <hip/hip_runtime.h>
#include <stdint.h>

#define H 512
#define KAUG 528
#define KT_N 33            // K tiles of 16 (528/16)
#define LROW 536           // LDS row stride in shorts (encoder)
#define NROW 32
#define WMAT_ELEMS (16 * KT_N * 4 * 512)   // encoder wpack per matrix: 1,081,344 shorts
#define T_DEC 32
#define B_TOT 4096

// decoder pack/weight geometry (shorts)
#define WDEC_BLK   67584        // per (chain,m): 33*4*64*8
#define PK_MT      16896        // 33*512
#define PK_G       (16 * PK_MT)          // 270,336
#define PK_CH      (8 * PK_G)            // 2,162,688
#define PK_BUF     (2 * PK_CH)           // 4,325,376

typedef __attribute__((ext_vector_type(8))) short short8;
typedef __attribute__((ext_vector_type(16))) float floatx16;
typedef __attribute__((ext_vector_type(4))) unsigned int uint4v;

__device__ __forceinline__ unsigned short f2bf(float x) {
  union { float f; unsigned int u; } v; v.f = x;
  unsigned int u = v.u;
  return (unsigned short)((u + 0x7FFFu + ((u >> 16) & 1u)) >> 16);
}
__device__ __forceinline__ float bf2f(unsigned short s) {
  union { unsigned int u; float f; } v; v.u = ((unsigned int)s) << 16;
  return v.f;
}
__device__ __forceinline__ float rcpf(float x) { return __builtin_amdgcn_rcpf(x); }
__device__ __forceinline__ float sigm(float x) { return rcpf(1.0f + __expf(-x)); }
__device__ __forceinline__ float tanh_f(float x) {
  return 1.0f - 2.0f * rcpf(1.0f + __expf(2.0f * x));
}

#define MFMA(A, B, C) __builtin_amdgcn_mfma_f32_32x32x16_bf16(A, B, C, 0, 0, 0)

// ---------------- prep: encoder bf16 weights (R1 layout, 2 matrices) ---------
__global__ void prep_enc(
    const float* __restrict__ Wh_s, const float* __restrict__ Wi_s, const float* __restrict__ b_s,
    const float* __restrict__ Wh_p, const float* __restrict__ Wi_p, const float* __restrict__ b_p,
    short* __restrict__ wpack)
{
  int idx = blockIdx.x * 256 + threadIdx.x;
  const int per = 2048 * KAUG;
  if (idx >= 2 * per) return;
  int mat = idx / per;
  int rem = idx - mat * per;
  int n = rem / KAUG;
  int ka = rem - n * KAUG;
  const float* Wh = mat ? Wh_p : Wh_s;
  const float* Wi = mat ? Wi_p : Wi_s;
  const float* bb = mat ? b_p  : b_s;
  float v;
  if (ka < 512)      v = Wh[n * 512 + ka];
  else if (ka < 516) v = Wi[n * 4 + (ka - 512)];
  else if (ka == 516) v = bb[n];
  else               v = 0.0f;
  int g = n >> 9, ntL = (n >> 5) & 15, ni = n & 31;
  int kt = ka >> 4, kh = (ka >> 3) & 1, ks = ka & 7;
  int lanep = kh * 32 + ni;
  wpack[(size_t)mat * WMAT_ELEMS +
        (((((size_t)ntL * KT_N + kt) * 4 + g) << 9) + (lanep << 3) + ks)] = (short)f2bf(v);
}

// ---------------- prep: decoder weights, per-(chain,m) LDS-slice layout ------
// wdec[chain][m][kt][gate][lane][j]; also zeroes the group-barrier slots.
__global__ void prep_dec(
    const float* __restrict__ Wh_d, const float* __restrict__ Wi_d, const float* __restrict__ b_d,
    const float* __restrict__ Wh_i, const float* __restrict__ Wi_i, const float* __restrict__ b_i,
    short* __restrict__ wdec, unsigned* __restrict__ bar)
{
  int idx = blockIdx.x * 256 + threadIdx.x;
  if (blockIdx.x == 0 && threadIdx.x < 256) {           // zero 16*80 barrier slots
    #pragma unroll
    for (int k = 0; k < 5; ++k) bar[threadIdx.x + 256 * k] = 0u;
  }
  if (idx >= 2 * 16 * WDEC_BLK) return;
  int chain = idx / (16 * WDEC_BLK);
  int rem = idx - chain * (16 * WDEC_BLK);
  int m = rem / WDEC_BLK;
  int r2 = rem - m * WDEC_BLK;
  int kt = r2 >> 11;                // /2048
  int r3 = r2 & 2047;
  int gate = r3 >> 9;
  int l = (r3 >> 3) & 63;
  int j = r3 & 7;
  int n = gate * 512 + m * 32 + (l & 31);
  int ka = kt * 16 + ((l >> 5) << 3) + j;
  const float* Wh = chain ? Wh_i : Wh_d;
  const float* Wi = chain ? Wi_i : Wi_d;
  const float* bb = chain ? b_i  : b_d;
  float v;
  if (ka < 512)       v = Wh[n * 512 + ka];
  else if (ka < 516)  v = Wi[n * 4 + (ka - 512)];
  else if (ka == 516) v = bb[n];
  else                v = 0.0f;
  wdec[idx] = (short)f2bf(v);
}

// ---------------- encoder LSTM step (R1 version, unchanged) ------------------
__device__ __forceinline__ void lstm_step_mfma(
    const short* hl, const short* __restrict__ wm,
    int lane, int wv, float c_reg[16], float hnew[16])
{
  int arow = lane & 31, ahalf = lane >> 5;
  const short* aptr = hl + arow * LROW + ahalf * 8;
  const short* bp = wm + (size_t)wv * (KT_N * 4 * 512) + (lane << 3);
  floatx16 ai = (floatx16)0.0f, af = (floatx16)0.0f, ag = (floatx16)0.0f, ao = (floatx16)0.0f;
  #pragma unroll 3
  for (int kt = 0; kt < KT_N; ++kt) {
    short8 a  = *(const short8*)(aptr + kt * 16);
    short8 b0 = *(const short8*)(bp);
    short8 b1 = *(const short8*)(bp + 512);
    short8 b2 = *(const short8*)(bp + 1024);
    short8 b3 = *(const short8*)(bp + 1536);
    bp += 2048;
    ai = MFMA(a, b0, ai); af = MFMA(a, b1, af);
    ag = MFMA(a, b2, ag); ao = MFMA(a, b3, ao);
  }
  #pragma unroll
  for (int r = 0; r < 16; ++r) {
    float si = sigm(ai[r]);
    float sf = sigm(af[r]);
    float tg = tanh_f(ag[r]);
    float so = sigm(ao[r]);
    float cn = sf * c_reg[r] + si * tg;
    c_reg[r] = cn;
    hnew[r] = so * tanh_f(cn);
  }
}

__device__ __forceinline__ void write_h(short* hl, int lane, int wv, const float hnew[16]) {
  int arow = lane & 31, ahalf = lane >> 5;
  int col = (wv << 5) + arow;
  #pragma unroll
  for (int r = 0; r < 16; ++r) {
    int row = (r & 3) + ((r >> 2) << 3) + (ahalf << 2);
    hl[row * LROW + col] = (short)f2bf(hnew[r]);
  }
}

// ---------------- encoder (R1 structure, known-good) -------------------------
__global__ __launch_bounds__(1024) void lstm_encoder(
    const float* __restrict__ speed, const float* __restrict__ pos,
    const short* __restrict__ wpack,
    short* __restrict__ h_enc, float* __restrict__ c_enc)
{
  __shared__ short hl[NROW * LROW];
  int tid = threadIdx.x;
  int b = blockIdx.x;
  int xcd = b & 7, slot = b >> 3;
  int enc = xcd >> 2;
  int rg = slot * 4 + (xcd & 3);
  int r0 = rg * 32;
  const float* xin = enc ? pos : speed;
  const short* wm = wpack + (size_t)enc * WMAT_ELEMS;

  for (int i = tid; i < NROW * LROW; i += 1024) hl[i] = 0;
  __syncthreads();
  if (tid < 32) hl[tid * LROW + 516] = (short)0x3F80;
  if (tid < 128) {
    int r = tid >> 2, c = tid & 3;
    hl[r * LROW + 512 + c] = (short)f2bf(xin[(r0 + r) * 64 + c]);
  }
  __syncthreads();

  int lane = tid & 63, wv = tid >> 6;
  float c_reg[16];
  #pragma unroll
  for (int r = 0; r < 16; ++r) c_reg[r] = 0.0f;
  float hnew[16];

  for (int t = 0; t < 16; ++t) {
    lstm_step_mfma(hl, wm, lane, wv, c_reg, hnew);
    __syncthreads();
    write_h(hl, lane, wv, hnew);
    if (t < 15 && tid < 128) {
      int r = tid >> 2, c = tid & 3;
      hl[r * LROW + 512 + c] = (short)f2bf(xin[(r0 + r) * 64 + (t + 1) * 4 + c]);
    }
    __syncthreads();
  }

  for (int i = tid; i < 32 * 512; i += 1024) {
    int r = i >> 9, k = i & 511;
    h_enc[((size_t)(enc * B_TOT + r0 + r) << 9) + k] = hl[r * LROW + k];
  }
  int arow = lane & 31, ahalf = lane >> 5;
  int col = (wv << 5) + arow;
  #pragma unroll
  for (int r = 0; r < 16; ++r) {
    int row = (r & 3) + ((r >> 2) << 3) + (ahalf << 2);
    c_enc[((size_t)(enc * B_TOT + r0 + row) << 9) + col] = c_reg[r];
  }
}

// ---------------- decoder v2: weight-stationary, h exchanged via L2 ----------
// 256 blocks = 2 chains x 8 groups(512 rows) x 16 col-slices(32 h-cols).
// Weights (135 KB) pinned in LDS; c in regs; h_pack (A-fragment layout) double-
// buffered in global, exchanged within the group each step (XCD-local by b&7).
// Group barrier: per-instance counters (zeroed by prep_dec each launch).
__device__ __forceinline__ void gbar(unsigned* slot) {
  __threadfence();
  __syncthreads();
  if (threadIdx.x == 0) {
    atomicAdd(slot, 1u);
    while (atomicAdd(slot, 0u) < 16u) __builtin_amdgcn_s_sleep(4);
  }
  __syncthreads();
  __threadfence();
}

__global__ __launch_bounds__(1024) void lstm_decoder(
    const float* __restrict__ speed, const float* __restrict__ pos,
    const short* __restrict__ wdec,
    const short* __restrict__ h_enc, const float* __restrict__ c_enc,
    const float* __restrict__ W_fs, const float* __restrict__ b_fs,
    const float* __restrict__ W_fc, const float* __restrict__ b_fc,
    const float* __restrict__ W_emb, const float* __restrict__ b_emb,
    short* __restrict__ hpk, unsigned* __restrict__ bar,
    float* __restrict__ out)
{
  __shared__ short wlds[WDEC_BLK];        // 135,168 B
  __shared__ short sc[16][16][40];        // 20,480 B per-wave transpose scratch

  int tid = threadIdx.x, b = blockIdx.x;
  int g = b & 7, s = b >> 3;
  int chain = s >> 4, m = s & 15;
  int lane = tid & 63, wv = tid >> 6;     // wv = mt (0..15)

  // stage weight slice to LDS (16B chunks)
  {
    const uint4v* src = (const uint4v*)(wdec + (size_t)(chain * 16 + m) * WDEC_BLK);
    uint4v* dst = (uint4v*)wlds;
    for (int i = tid; i < WDEC_BLK / 8; i += 1024) dst[i] = src[i];
  }

  short* pkc = hpk + (size_t)chain * PK_CH + (size_t)g * PK_G;  // + buf*PK_BUF

  // ---- init pack buf0 (mt=m rows fully) and buf1 tail (bias/zeros) ----------
  {
    const float* lastx = chain ? pos : speed;
    for (int i = tid; i < 32 * KAUG; i += 1024) {
      int row = i / KAUG, ka = i - row * KAUG;
      int grow = g * 512 + m * 32 + row;
      float v;
      if (ka < 512)
        v = bf2f((unsigned short)h_enc[((size_t)grow << 9) + ka])
          + bf2f((unsigned short)h_enc[((size_t)(B_TOT + grow) << 9) + ka]);
      else if (ka < 516) v = lastx[grow * 64 + 60 + (ka - 512)];
      else if (ka == 516) v = 1.0f;
      else v = 0.0f;
      int kt = ka >> 4, l = (row & 31) + 32 * ((ka >> 3) & 1), j = ka & 7;
      size_t off = (size_t)m * PK_MT + (size_t)kt * 512 + l * 8 + j;
      pkc[off] = (short)f2bf(v);
      if (kt == 32) pkc[PK_BUF + off] = (ka == 516) ? (short)0x3F80 : (short)0;
    }
  }

  // ---- c init (D-layout: col = lane&31 within slice, rows from regs) --------
  float c_reg[16];
  {
    int col = m * 32 + (lane & 31);
    #pragma unroll
    for (int r = 0; r < 16; ++r) {
      int row = g * 512 + wv * 32 + (r & 3) + ((r >> 2) << 3) + ((lane >> 5) << 2);
      size_t gi = ((size_t)row << 9) + col;
      c_reg[r] = c_enc[gi] + c_enc[gi + (((size_t)B_TOT) << 9)];
    }
  }

  unsigned* bc = bar + (chain * 8 + g) * 80;
  int inst = 0;
  gbar(bc + inst); ++inst;                 // all blocks' init visible

  int lrow  = lane & 15;
  int kt_l  = lane >> 5;
  int halfb = (lane >> 4) & 1;
  int rdoff = lrow * 40 + kt_l * 16 + halfb * 8;
  short* scw = &sc[wv][0][0];

  for (int t = 0; t < T_DEC; ++t) {
    const short* pkR = pkc + (size_t)(t & 1) * PK_BUF;
    short*       pkW = pkc + (size_t)((t + 1) & 1) * PK_BUF;

    // ---- gates = h_aug @ W.T : A from global pack (L2), B from LDS ----------
    floatx16 ai = (floatx16)0.0f, af = (floatx16)0.0f,
             ag = (floatx16)0.0f, ao = (floatx16)0.0f;
    const short* ap = pkR + (size_t)wv * PK_MT + lane * 8;
    short8 a = *(const short8*)ap;
    #pragma unroll 1
    for (int kt = 0; kt < KT_N; ++kt) {
      int ktn = (kt < 32) ? kt + 1 : 32;
      short8 an = *(const short8*)(ap + (size_t)ktn * 512);
      const short* bb = wlds + ((kt << 2) << 9) + lane * 8;
      short8 b0 = *(const short8*)(bb);
      short8 b1 = *(const short8*)(bb + 512);
      short8 b2 = *(const short8*)(bb + 1024);
      short8 b3 = *(const short8*)(bb + 1536);
      ai = MFMA(a, b0, ai); af = MFMA(a, b1, af);
      ag = MFMA(a, b2, ag); ao = MFMA(a, b3, ao);
      a = an;
    }

    // ---- activations & cell update -----------------------------------------
    float hnew[16];
    #pragma unroll
    for (int r = 0; r < 16; ++r) {
      float si = sigm(ai[r]);
      float sf = sigm(af[r]);
      float tg = tanh_f(ag[r]);
      float so = sigm(ao[r]);
      float cn = sf * c_reg[r] + si * tg;
      c_reg[r] = cn;
      hnew[r] = so * tanh_f(cn);
    }

    // ---- transpose h_new (D-layout) -> pack layout, 2 row-halves -----------
    #pragma unroll
    for (int p = 0; p < 2; ++p) {
      #pragma unroll
      for (int rr = 0; rr < 8; ++rr) {
        int r = p * 8 + rr;
        int loc = (r & 3) + ((r >> 2) & 1) * 8 + ((lane >> 5) << 2);
        scw[loc * 40 + (lane & 31)] = (short)f2bf(hnew[r]);
      }
      asm volatile("s_waitcnt lgkmcnt(0)" ::: "memory");
      short8 v = *(const short8*)(scw + rdoff);
      int l = 16 * p + lrow + 32 * halfb;
      *(short8*)(pkW + ((size_t)wv * 33 + (2 * m + kt_l)) * 512 + (size_t)l * 8) = v;
      asm volatile("s_waitcnt lgkmcnt(0)" ::: "memory");
    }

    gbar(bc + inst); ++inst;               // h_new complete group-wide

    // ---- heads for this block's 32 group-rows [m*32, m*32+32) ---------------
    #pragma unroll 1
    for (int r = 0; r < 2; ++r) {
      int q = wv * 2 + r;                  // local row 0..31
      int grow = g * 512 + m * 32 + q;
      const short8 hvs = *(const short8*)(pkW + (size_t)m * PK_MT +
                                          (size_t)(lane >> 1) * 512 +
                                          (size_t)(q + 32 * (lane & 1)) * 8);
      float hv[8];
      #pragma unroll
      for (int j = 0; j < 8; ++j) hv[j] = bf2f((unsigned short)hvs[j]);
      if (chain == 0) {
        float p0 = 0.f, p1 = 0.f, p2 = 0.f, p3 = 0.f;
        #pragma unroll
        for (int j = 0; j < 8; ++j) {
          p0 += hv[j] * W_fs[0 * 512 + lane * 8 + j];
          p1 += hv[j] * W_fs[1 * 512 + lane * 8 + j];
          p2 += hv[j] * W_fs[2 * 512 + lane * 8 + j];
          p3 += hv[j] * W_fs[3 * 512 + lane * 8 + j];
        }
        #pragma unroll
        for (int off = 32; off > 0; off >>= 1) {
          p0 += __shfl_xor(p0, off);
          p1 += __shfl_xor(p1, off);
          p2 += __shfl_xor(p2, off);
          p3 += __shfl_xor(p3, off);
        }
        float s0 = fminf(fmaxf(p0 + b_fs[0], -100.0f), 100.0f);
        float s1 = fminf(fmaxf(p1 + b_fs[1], -100.0f), 100.0f);
        float s2 = fminf(fmaxf(p2 + b_fs[2], -100.0f), 100.0f);
        float s3 = fminf(fmaxf(p3 + b_fs[3], -100.0f), 100.0f);
        if (lane < 4) {
          float v = (lane == 0) ? s0 : (lane == 1) ? s1 : (lane == 2) ? s2 : s3;
          out[(size_t)grow * 128 + t * 4 + lane] = v;                 // speed out
          pkW[(size_t)m * PK_MT + 32 * 512 + q * 8 + lane] = (short)f2bf(v); // ls
        }
      } else {
        float p0 = 0.f, p1 = 0.f;
        #pragma unroll
        for (int j = 0; j < 8; ++j) {
          p0 += hv[j] * W_fc[0 * 512 + lane * 8 + j];
          p1 += hv[j] * W_fc[1 * 512 + lane * 8 + j];
        }
        #pragma unroll
        for (int off = 32; off > 0; off >>= 1) {
          p0 += __shfl_xor(p0, off);
          p1 += __shfl_xor(p1, off);
        }
        float it0 = fmaxf(p0 + b_fc[0], 0.0f);
        float it1 = fmaxf(p1 + b_fc[1], 0.0f);
        if (lane < 4) {
          float lp = fmaxf(W_emb[lane * 2] * it0 + W_emb[lane * 2 + 1] * it1 + b_emb[lane], 0.0f);
          pkW[(size_t)m * PK_MT + 32 * 512 + q * 8 + lane] = (short)f2bf(lp); // lp
        }
        if (t == T_DEC - 1 && lane < 2) {
          float mx = fmaxf(it0, it1);
          float e0 = __expf(it0 - mx), e1 = __expf(it1 - mx);
          float v = ((lane == 0) ? e0 : e1) * rcpf(e0 + e1);
          out[(size_t)524288 + (size_t)grow * 2 + lane] = v;          // crossing
        }
      }
    }

    gbar(bc + inst); ++inst;               // x feedback complete
  }
}

extern "C" void kernel_launch(void* const* d_in, const int* in_sizes, int n_in,
                              void* d_out, int out_size, void* d_ws, size_t ws_size,
                              hipStream_t stream)
{
  const float* speed    = (const float*)d_in[0];
  const float* pos      = (const float*)d_in[1];
  const float* enc_s_Wi = (const float*)d_in[2];
  const float* enc_s_Wh = (const float*)d_in[3];
  const float* enc_s_b  = (const float*)d_in[4];
  const float* enc_p_Wi = (const float*)d_in[5];
  const float* enc_p_Wh = (const float*)d_in[6];
  const float* enc_p_b  = (const float*)d_in[7];
  const float* dec_s_Wi = (const float*)d_in[8];
  const float* dec_s_Wh = (const float*)d_in[9];
  const float* dec_s_b  = (const float*)d_in[10];
  const float* dec_i_Wi = (const float*)d_in[11];
  const float* dec_i_Wh = (const float*)d_in[12];
  const float* dec_i_b  = (const float*)d_in[13];
  const float* W_fs     = (const float*)d_in[14];
  const float* b_fs     = (const float*)d_in[15];
  const float* W_fc     = (const float*)d_in[16];
  const float* b_fc     = (const float*)d_in[17];
  const float* W_emb    = (const float*)d_in[18];
  const float* b_emb    = (const float*)d_in[19];
  float* out = (float*)d_out;

  char* ws = (char*)d_ws;
  short* wpack_enc = (short*)ws;                        // 4,325,376 B
  short* wdec      = (short*)(ws + 4325376);            // 4,325,376 B
  short* h_enc     = (short*)(ws + 8650752);            // 8,388,608 B
  float* c_enc     = (float*)(ws + 17039360);           // 16,777,216 B
  short* hpk       = (short*)(ws + 33816576);           // 17,301,504 B
  unsigned* bar    = (unsigned*)(ws + 51118080);        // 5,120 B

  prep_enc<<<8448, 256, 0, stream>>>(
      enc_s_Wh, enc_s_Wi, enc_s_b,
      enc_p_Wh, enc_p_Wi, enc_p_b,
      wpack_enc);
  prep_dec<<<8448, 256, 0, stream>>>(
      dec_s_Wh, dec_s_Wi, dec_s_b,
      dec_i_Wh, dec_i_Wi, dec_i_b,
      wdec, bar);
  lstm_encoder<<<256, 1024, 0, stream>>>(speed, pos, wpack_enc, h_enc, c_enc);
  // 152 KB LDS/block -> exactly 1 block/CU, grid 256 = CU count: all group
  // members co-resident for the spin barrier.
  lstm_decoder<<<256, 1024, 0, stream>>>(speed, pos, wdec, h_enc, c_enc,
                                         W_fs, b_fs, W_fc, b_fc, W_emb, b_emb,
                                         hpk, bar, out);
}

// Round 6
// 1315.212 us; speedup vs baseline: 7.5146x; 7.5146x over previous
//
#include <hip/hip_runtime.h>
#include <stdint.h>

#define H 512
#define KAUG 528
#define KT_N 33            // K tiles of 16 (528/16)
#define LROW 536           // LDS row stride in shorts (16B aligned, 2-way bank alias = free)
#define NROW 32
#define WMAT_ELEMS (16 * KT_N * 4 * 512)   // 16 ntL * 33 kt * 4 gates * 512 = 1,081,344
#define T_DEC 32
#define B_TOT 4096

typedef __attribute__((ext_vector_type(8))) short short8;
typedef __attribute__((ext_vector_type(16))) float floatx16;

__device__ __forceinline__ unsigned short f2bf(float x) {
  union { float f; unsigned int u; } v; v.f = x;
  unsigned int u = v.u;
  return (unsigned short)((u + 0x7FFFu + ((u >> 16) & 1u)) >> 16);
}
__device__ __forceinline__ float bf2f(unsigned short s) {
  union { unsigned int u; float f; } v; v.u = ((unsigned int)s) << 16;
  return v.f;
}
__device__ __forceinline__ float rcpf(float x) { return __builtin_amdgcn_rcpf(x); }
__device__ __forceinline__ float sigm(float x) { return rcpf(1.0f + __expf(-x)); }
__device__ __forceinline__ float tanh_f(float x) {
  return 1.0f - 2.0f * rcpf(1.0f + __expf(2.0f * x));
}

#define MFMA(A, B, C) __builtin_amdgcn_mfma_f32_32x32x16_bf16(A, B, C, 0, 0, 0)

// ---------------- prep: build augmented tile-packed bf16 weights (R1) --------
// W_aug[n][ka]: ka<512 -> Wh[n][ka]; 512..515 -> Wi[n][ka-512]; 516 -> b[n]; else 0
//   idx = ((ntL*33 + kt)*4 + g)*512 + lanep*8 + ks
__global__ void prep_weights(
    const float* __restrict__ Wh_s, const float* __restrict__ Wi_s, const float* __restrict__ b_s,
    const float* __restrict__ Wh_p, const float* __restrict__ Wi_p, const float* __restrict__ b_p,
    const float* __restrict__ Wh_d, const float* __restrict__ Wi_d, const float* __restrict__ b_d,
    const float* __restrict__ Wh_i, const float* __restrict__ Wi_i, const float* __restrict__ b_i,
    short* __restrict__ wpack)
{
  int idx = blockIdx.x * 256 + threadIdx.x;
  const int per = 2048 * KAUG;
  if (idx >= 4 * per) return;
  int mat = idx / per;
  int rem = idx - mat * per;
  int n = rem / KAUG;
  int ka = rem - n * KAUG;
  const float* Wh; const float* Wi; const float* bb;
  if (mat == 0)      { Wh = Wh_s; Wi = Wi_s; bb = b_s; }
  else if (mat == 1) { Wh = Wh_p; Wi = Wi_p; bb = b_p; }
  else if (mat == 2) { Wh = Wh_d; Wi = Wi_d; bb = b_d; }
  else               { Wh = Wh_i; Wi = Wi_i; bb = b_i; }
  float v;
  if (ka < 512)      v = Wh[n * 512 + ka];
  else if (ka < 516) v = Wi[n * 4 + (ka - 512)];
  else if (ka == 516) v = bb[n];
  else               v = 0.0f;
  int g = n >> 9, ntL = (n >> 5) & 15, ni = n & 31;
  int kt = ka >> 4, kh = (ka >> 3) & 1, ks = ka & 7;
  int lanep = kh * 32 + ni;
  wpack[(size_t)mat * WMAT_ELEMS +
        (((((size_t)ntL * KT_N + kt) * 4 + g) << 9) + (lanep << 3) + ks)] = (short)f2bf(v);
}

// ---------------- encoder LSTM step (R1 version: 16 waves, 33 kt) ------------
__device__ __forceinline__ void lstm_step_mfma(
    const short* hl, const short* __restrict__ wm,
    int lane, int wv, float c_reg[16], float hnew[16])
{
  int arow = lane & 31, ahalf = lane >> 5;
  const short* aptr = hl + arow * LROW + ahalf * 8;
  const short* bp = wm + (size_t)wv * (KT_N * 4 * 512) + (lane << 3);
  floatx16 ai = (floatx16)0.0f, af = (floatx16)0.0f, ag = (floatx16)0.0f, ao = (floatx16)0.0f;
  #pragma unroll 3
  for (int kt = 0; kt < KT_N; ++kt) {
    short8 a  = *(const short8*)(aptr + kt * 16);
    short8 b0 = *(const short8*)(bp);
    short8 b1 = *(const short8*)(bp + 512);
    short8 b2 = *(const short8*)(bp + 1024);
    short8 b3 = *(const short8*)(bp + 1536);
    bp += 2048;
    ai = MFMA(a, b0, ai); af = MFMA(a, b1, af);
    ag = MFMA(a, b2, ag); ao = MFMA(a, b3, ao);
  }
  #pragma unroll
  for (int r = 0; r < 16; ++r) {
    float si = sigm(ai[r]);
    float sf = sigm(af[r]);
    float tg = tanh_f(ag[r]);
    float so = sigm(ao[r]);
    float cn = sf * c_reg[r] + si * tg;
    c_reg[r] = cn;
    hnew[r] = so * tanh_f(cn);
  }
}

__device__ __forceinline__ void write_h16(short* hl, int lane, int wv, const float hnew[16]) {
  int arow = lane & 31, ahalf = lane >> 5;
  int col = (wv << 5) + arow;
  #pragma unroll
  for (int r = 0; r < 16; ++r) {
    int row = (r & 3) + ((r >> 2) << 3) + (ahalf << 2);
    hl[row * LROW + col] = (short)f2bf(hnew[r]);
  }
}

// ---------------- encoder: dbuf h -> ONE barrier per step --------------------
__global__ __launch_bounds__(1024) void lstm_encoder(
    const float* __restrict__ speed, const float* __restrict__ pos,
    const short* __restrict__ wpack,
    short* __restrict__ h_enc, float* __restrict__ c_enc)
{
  __shared__ short hl[2][NROW * LROW];
  int tid = threadIdx.x;
  int b = blockIdx.x;
  int xcd = b & 7, slot = b >> 3;
  int enc = xcd >> 2;               // XCDs 0-3: speed, 4-7: pos (L2 locality)
  int rg = slot * 4 + (xcd & 3);    // 0..127
  int r0 = rg * 32;
  const float* xin = enc ? pos : speed;
  const short* wm = wpack + (size_t)enc * WMAT_ELEMS;

  {
    short* hz = &hl[0][0];
    for (int i = tid; i < 2 * NROW * LROW; i += 1024) hz[i] = 0;
  }
  __syncthreads();
  if (tid < 64) hl[tid >> 5][(tid & 31) * LROW + 516] = (short)0x3F80;  // bias, both bufs
  if (tid < 128) {
    int r = tid >> 2, c = tid & 3;
    hl[0][r * LROW + 512 + c] = (short)f2bf(xin[(r0 + r) * 64 + c]);    // x_0
  }
  __syncthreads();

  int lane = tid & 63, wv = tid >> 6;   // wv in [0,16)
  float c_reg[16];
  #pragma unroll
  for (int r = 0; r < 16; ++r) c_reg[r] = 0.0f;
  float hnew[16];

  for (int t = 0; t < 16; ++t) {
    const short* cb = hl[t & 1];
    short* nb = &hl[(t + 1) & 1][0];
    lstm_step_mfma(cb, wm, lane, wv, c_reg, hnew);
    write_h16(nb, lane, wv, hnew);
    if (t < 15 && tid < 128) {
      int r = tid >> 2, c = tid & 3;
      nb[r * LROW + 512 + c] = (short)f2bf(xin[(r0 + r) * 64 + (t + 1) * 4 + c]);
    }
    __syncthreads();
  }

  // final h lives in hl[0] (t=15 wrote buf (15+1)&1 = 0)
  for (int i = tid; i < 32 * 512; i += 1024) {
    int r = i >> 9, k = i & 511;
    h_enc[((size_t)(enc * B_TOT + r0 + r) << 9) + k] = hl[0][r * LROW + k];
  }
  int arow = lane & 31, ahalf = lane >> 5;
  int col = (wv << 5) + arow;
  #pragma unroll
  for (int r = 0; r < 16; ++r) {
    int row = (r & 3) + ((r >> 2) << 3) + (ahalf << 2);
    c_enc[((size_t)(enc * B_TOT + r0 + row) << 9) + col] = c_reg[r];
  }
}

// ---------------- decoder: 512 thr, dbuf h, x-direct activation --------------
// 8 waves: wave wv owns h-cols [wv*64, wv*64+64) (jt=0,1). k-loop runs kt 0..31
// only (Wh·h); the Wi·x + b contribution is added in f32 during activation from
// per-thread register Wx/b and a tiny f32 x buffer in LDS (double-buffered).
// Two barriers/step: [k-loop+act+write_h(nb)] B1 [heads -> out + x(nb)] B2.
__global__ __launch_bounds__(512) void lstm_decoder(
    const float* __restrict__ speed, const float* __restrict__ pos,
    const short* __restrict__ wpack,
    const float* __restrict__ dWi_s, const float* __restrict__ db_s,
    const float* __restrict__ dWi_i, const float* __restrict__ db_i,
    const short* __restrict__ h_enc, const float* __restrict__ c_enc,
    const float* __restrict__ W_fs, const float* __restrict__ b_fs,
    const float* __restrict__ W_fc, const float* __restrict__ b_fc,
    const float* __restrict__ W_emb, const float* __restrict__ b_emb,
    float* __restrict__ out)
{
  __shared__ short hl[2][NROW * LROW];
  __shared__ float xs[2][32][4];
  int tid = threadIdx.x;
  int b = blockIdx.x;
  int xcd = b & 7, slot = b >> 3;
  int chain = xcd >> 2;
  int rg = slot * 4 + (xcd & 3);
  int r0 = rg * 32;
  const short* wm = wpack + (size_t)(2 + chain) * WMAT_ELEMS;
  int lane = tid & 63, wv = tid >> 6;          // wv in [0,8)
  int arow = lane & 31, ahalf = lane >> 5;

  // init hl[0] = h_se + h_pe (cols 0..511; cols 512+ never read in decoder)
  for (int i = tid; i < 32 * 512; i += 512) {
    int r = i >> 9, k = i & 511;
    float h0 = bf2f((unsigned short)h_enc[((size_t)(r0 + r) << 9) + k])
             + bf2f((unsigned short)h_enc[((size_t)(B_TOT + r0 + r) << 9) + k]);
    hl[0][r * LROW + k] = (short)f2bf(h0);
  }
  // x(0) = last input frame, f32
  {
    const float* last = chain ? pos : speed;
    if (tid < 128) {
      int r = tid >> 2, c = tid & 3;
      xs[0][r][c] = last[(r0 + r) * 64 + 60 + c];
    }
  }

  // c init (D-layout)
  float c_reg[2][16];
  #pragma unroll
  for (int jt = 0; jt < 2; ++jt) {
    int col = wv * 64 + jt * 32 + arow;
    #pragma unroll
    for (int r = 0; r < 16; ++r) {
      int row = (r & 3) + ((r >> 2) << 3) + (ahalf << 2);
      size_t gi = ((size_t)(r0 + row) << 9) + col;
      c_reg[jt][r] = c_enc[gi] + c_enc[gi + (((size_t)B_TOT) << 9)];
    }
  }

  // per-thread Wx/b for this thread's two output columns (loaded once)
  const float* dWi = chain ? dWi_i : dWi_s;
  const float* dbv = chain ? db_i  : db_s;
  float wx[2][4][4], wb[2][4];
  #pragma unroll
  for (int jt = 0; jt < 2; ++jt) {
    int col = wv * 64 + jt * 32 + arow;
    #pragma unroll
    for (int g = 0; g < 4; ++g) {
      int n = g * 512 + col;
      #pragma unroll
      for (int c = 0; c < 4; ++c) wx[jt][g][c] = dWi[n * 4 + c];
      wb[jt][g] = dbv[n];
    }
  }

  // head weights in registers (R0-proven at 512 threads)
  float wro[4][8], hb[4], we[8], be[4];
  if (chain == 0) {
    #pragma unroll
    for (int o = 0; o < 4; ++o) {
      #pragma unroll
      for (int j = 0; j < 8; ++j) wro[o][j] = W_fs[o * 512 + lane * 8 + j];
      hb[o] = b_fs[o];
    }
  } else {
    #pragma unroll
    for (int o = 0; o < 2; ++o) {
      #pragma unroll
      for (int j = 0; j < 8; ++j) wro[o][j] = W_fc[o * 512 + lane * 8 + j];
      hb[o] = b_fc[o];
    }
    #pragma unroll
    for (int j = 0; j < 8; ++j) we[j] = W_emb[j];
    #pragma unroll
    for (int o = 0; o < 4; ++o) be[o] = b_emb[o];
  }
  __syncthreads();

  for (int t = 0; t < T_DEC; ++t) {
    const short* cb = hl[t & 1];
    short* nb = &hl[(t + 1) & 1][0];
    const float (*xr)[4] = xs[t & 1];
    float (*xw)[4] = xs[(t + 1) & 1];

    // ---- k-loop (Wh·h only, 32 kt) + x-direct activation + write_h ----------
    const short* aptr = cb + arow * LROW + ahalf * 8;
    #pragma unroll
    for (int jt = 0; jt < 2; ++jt) {
      int ntL = wv * 2 + jt;
      const short* bp = wm + (size_t)ntL * (KT_N * 4 * 512) + (lane << 3);
      floatx16 ai = (floatx16)0.0f, af = (floatx16)0.0f,
               ag = (floatx16)0.0f, ao = (floatx16)0.0f;
      #pragma unroll 2
      for (int kt = 0; kt < 32; ++kt) {
        short8 a  = *(const short8*)(aptr + kt * 16);
        short8 b0 = *(const short8*)(bp);
        short8 b1 = *(const short8*)(bp + 512);
        short8 b2 = *(const short8*)(bp + 1024);
        short8 b3 = *(const short8*)(bp + 1536);
        bp += 2048;
        ai = MFMA(a, b0, ai); af = MFMA(a, b1, af);
        ag = MFMA(a, b2, ag); ao = MFMA(a, b3, ao);
      }
      int col = wv * 64 + jt * 32 + arow;
      #pragma unroll
      for (int r = 0; r < 16; ++r) {
        int row = (r & 3) + ((r >> 2) << 3) + (ahalf << 2);
        float x0 = xr[row][0], x1 = xr[row][1], x2 = xr[row][2], x3 = xr[row][3];
        float gi = ai[r] + wb[jt][0] + wx[jt][0][0]*x0 + wx[jt][0][1]*x1 + wx[jt][0][2]*x2 + wx[jt][0][3]*x3;
        float gf = af[r] + wb[jt][1] + wx[jt][1][0]*x0 + wx[jt][1][1]*x1 + wx[jt][1][2]*x2 + wx[jt][1][3]*x3;
        float gg = ag[r] + wb[jt][2] + wx[jt][2][0]*x0 + wx[jt][2][1]*x1 + wx[jt][2][2]*x2 + wx[jt][2][3]*x3;
        float go = ao[r] + wb[jt][3] + wx[jt][3][0]*x0 + wx[jt][3][1]*x1 + wx[jt][3][2]*x2 + wx[jt][3][3]*x3;
        float cn = sigm(gf) * c_reg[jt][r] + sigm(gi) * tanh_f(gg);
        c_reg[jt][r] = cn;
        nb[row * LROW + col] = (short)f2bf(sigm(go) * tanh_f(cn));
      }
    }
    __syncthreads();                               // B1: h(t+1) complete in nb

    // ---- heads: wave wv handles rows [wv*4, wv*4+4) of nb -------------------
    #pragma unroll 1
    for (int r = 0; r < 4; ++r) {
      int row = wv * 4 + r;
      const short8 hvs = *(const short8*)(nb + row * LROW + lane * 8);
      float hv[8];
      #pragma unroll
      for (int j = 0; j < 8; ++j) hv[j] = bf2f((unsigned short)hvs[j]);
      if (chain == 0) {
        float p0 = 0.f, p1 = 0.f, p2 = 0.f, p3 = 0.f;
        #pragma unroll
        for (int j = 0; j < 8; ++j) {
          p0 += hv[j] * wro[0][j];
          p1 += hv[j] * wro[1][j];
          p2 += hv[j] * wro[2][j];
          p3 += hv[j] * wro[3][j];
        }
        #pragma unroll
        for (int off = 32; off > 0; off >>= 1) {
          p0 += __shfl_xor(p0, off);
          p1 += __shfl_xor(p1, off);
          p2 += __shfl_xor(p2, off);
          p3 += __shfl_xor(p3, off);
        }
        float s0 = fminf(fmaxf(p0 + hb[0], -100.0f), 100.0f);
        float s1 = fminf(fmaxf(p1 + hb[1], -100.0f), 100.0f);
        float s2 = fminf(fmaxf(p2 + hb[2], -100.0f), 100.0f);
        float s3 = fminf(fmaxf(p3 + hb[3], -100.0f), 100.0f);
        if (lane < 4) {
          float v = (lane == 0) ? s0 : (lane == 1) ? s1 : (lane == 2) ? s2 : s3;
          out[(size_t)(r0 + row) * 128 + t * 4 + lane] = v;   // speed_outputs
          xw[row][lane] = v;                                  // ls feedback (f32)
        }
      } else {
        float p0 = 0.f, p1 = 0.f;
        #pragma unroll
        for (int j = 0; j < 8; ++j) {
          p0 += hv[j] * wro[0][j];
          p1 += hv[j] * wro[1][j];
        }
        #pragma unroll
        for (int off = 32; off > 0; off >>= 1) {
          p0 += __shfl_xor(p0, off);
          p1 += __shfl_xor(p1, off);
        }
        float it0 = fmaxf(p0 + hb[0], 0.0f);
        float it1 = fmaxf(p1 + hb[1], 0.0f);
        if (lane < 4) {
          float lp = fmaxf(we[lane * 2] * it0 + we[lane * 2 + 1] * it1 + be[lane], 0.0f);
          xw[row][lane] = lp;                                 // lp feedback (f32)
        }
        if (t == T_DEC - 1 && lane < 2) {
          float m = fmaxf(it0, it1);
          float e0 = __expf(it0 - m), e1 = __expf(it1 - m);
          float v = ((lane == 0) ? e0 : e1) * rcpf(e0 + e1);
          out[(size_t)524288 + (size_t)(r0 + row) * 2 + lane] = v; // crossing
        }
      }
    }
    __syncthreads();                               // B2: x(t+1) complete in xw
  }
}

extern "C" void kernel_launch(void* const* d_in, const int* in_sizes, int n_in,
                              void* d_out, int out_size, void* d_ws, size_t ws_size,
                              hipStream_t stream)
{
  const float* speed    = (const float*)d_in[0];
  const float* pos      = (const float*)d_in[1];
  const float* enc_s_Wi = (const float*)d_in[2];
  const float* enc_s_Wh = (const float*)d_in[3];
  const float* enc_s_b  = (const float*)d_in[4];
  const float* enc_p_Wi = (const float*)d_in[5];
  const float* enc_p_Wh = (const float*)d_in[6];
  const float* enc_p_b  = (const float*)d_in[7];
  const float* dec_s_Wi = (const float*)d_in[8];
  const float* dec_s_Wh = (const float*)d_in[9];
  const float* dec_s_b  = (const float*)d_in[10];
  const float* dec_i_Wi = (const float*)d_in[11];
  const float* dec_i_Wh = (const float*)d_in[12];
  const float* dec_i_b  = (const float*)d_in[13];
  const float* W_fs     = (const float*)d_in[14];
  const float* b_fs     = (const float*)d_in[15];
  const float* W_fc     = (const float*)d_in[16];
  const float* b_fc     = (const float*)d_in[17];
  const float* W_emb    = (const float*)d_in[18];
  const float* b_emb    = (const float*)d_in[19];
  float* out = (float*)d_out;

  char* ws = (char*)d_ws;
  short* wpack = (short*)ws;                 // 4 x 2,162,688 B = 8,650,752 B
  short* h_enc = (short*)(ws + 8650752);     // 2 x 4096 x 512 bf16 = 8,388,608 B
  float* c_enc = (float*)(ws + 17039360);    // 2 x 4096 x 512 f32  = 16,777,216 B

  prep_weights<<<16896, 256, 0, stream>>>(
      enc_s_Wh, enc_s_Wi, enc_s_b,
      enc_p_Wh, enc_p_Wi, enc_p_b,
      dec_s_Wh, dec_s_Wi, dec_s_b,
      dec_i_Wh, dec_i_Wi, dec_i_b,
      wpack);
  lstm_encoder<<<256, 1024, 0, stream>>>(speed, pos, wpack, h_enc, c_enc);
  lstm_decoder<<<256, 512, 0, stream>>>(speed, pos, wpack,
                                        dec_s_Wi, dec_s_b, dec_i_Wi, dec_i_b,
                                        h_enc, c_enc,
                                        W_fs, b_fs, W_fc, b_fc, W_emb, b_emb, out);
}

// Round 7
// 1291.031 us; speedup vs baseline: 7.6554x; 1.0187x over previous
//
#include <hip/hip_runtime.h>
#include <stdint.h>

#define H 512
#define KAUG 528
#define KT_N 33            // K tiles of 16 (528/16)
#define LROW 536           // LDS row stride in shorts (16B aligned, 2-way bank alias = free)
#define NROW 32
#define WMAT_ELEMS (16 * KT_N * 4 * 512)   // 16 ntL * 33 kt * 4 gates * 512 = 1,081,344
#define T_DEC 32
#define B_TOT 4096

typedef __attribute__((ext_vector_type(8))) short short8;
typedef __attribute__((ext_vector_type(16))) float floatx16;

__device__ __forceinline__ unsigned short f2bf(float x) {
  union { float f; unsigned int u; } v; v.f = x;
  unsigned int u = v.u;
  return (unsigned short)((u + 0x7FFFu + ((u >> 16) & 1u)) >> 16);
}
__device__ __forceinline__ float bf2f(unsigned short s) {
  union { unsigned int u; float f; } v; v.u = ((unsigned int)s) << 16;
  return v.f;
}
__device__ __forceinline__ float rcpf(float x) { return __builtin_amdgcn_rcpf(x); }
__device__ __forceinline__ float sigm(float x) { return rcpf(1.0f + __expf(-x)); }
__device__ __forceinline__ float tanh_f(float x) {
  return 1.0f - 2.0f * rcpf(1.0f + __expf(2.0f * x));
}

#define MFMA(A, B, C) __builtin_amdgcn_mfma_f32_32x32x16_bf16(A, B, C, 0, 0, 0)

// ---------------- prep: build augmented tile-packed bf16 weights (R1) --------
// W_aug[n][ka]: ka<512 -> Wh[n][ka]; 512..515 -> Wi[n][ka-512]; 516 -> b[n]; else 0
//   idx = ((ntL*33 + kt)*4 + g)*512 + lanep*8 + ks
__global__ void prep_weights(
    const float* __restrict__ Wh_s, const float* __restrict__ Wi_s, const float* __restrict__ b_s,
    const float* __restrict__ Wh_p, const float* __restrict__ Wi_p, const float* __restrict__ b_p,
    const float* __restrict__ Wh_d, const float* __restrict__ Wi_d, const float* __restrict__ b_d,
    const float* __restrict__ Wh_i, const float* __restrict__ Wi_i, const float* __restrict__ b_i,
    short* __restrict__ wpack)
{
  int idx = blockIdx.x * 256 + threadIdx.x;
  const int per = 2048 * KAUG;
  if (idx >= 4 * per) return;
  int mat = idx / per;
  int rem = idx - mat * per;
  int n = rem / KAUG;
  int ka = rem - n * KAUG;
  const float* Wh; const float* Wi; const float* bb;
  if (mat == 0)      { Wh = Wh_s; Wi = Wi_s; bb = b_s; }
  else if (mat == 1) { Wh = Wh_p; Wi = Wi_p; bb = b_p; }
  else if (mat == 2) { Wh = Wh_d; Wi = Wi_d; bb = b_d; }
  else               { Wh = Wh_i; Wi = Wi_i; bb = b_i; }
  float v;
  if (ka < 512)      v = Wh[n * 512 + ka];
  else if (ka < 516) v = Wi[n * 4 + (ka - 512)];
  else if (ka == 516) v = bb[n];
  else               v = 0.0f;
  int g = n >> 9, ntL = (n >> 5) & 15, ni = n & 31;
  int kt = ka >> 4, kh = (ka >> 3) & 1, ks = ka & 7;
  int lanep = kh * 32 + ni;
  wpack[(size_t)mat * WMAT_ELEMS +
        (((((size_t)ntL * KT_N + kt) * 4 + g) << 9) + (lanep << 3) + ks)] = (short)f2bf(v);
}

// ---------------- encoder LSTM step (R1 version: 16 waves, 33 kt) ------------
__device__ __forceinline__ void lstm_step_mfma(
    const short* hl, const short* __restrict__ wm,
    int lane, int wv, float c_reg[16], float hnew[16])
{
  int arow = lane & 31, ahalf = lane >> 5;
  const short* aptr = hl + arow * LROW + ahalf * 8;
  const short* bp = wm + (size_t)wv * (KT_N * 4 * 512) + (lane << 3);
  floatx16 ai = (floatx16)0.0f, af = (floatx16)0.0f, ag = (floatx16)0.0f, ao = (floatx16)0.0f;
  #pragma unroll 3
  for (int kt = 0; kt < KT_N; ++kt) {
    short8 a  = *(const short8*)(aptr + kt * 16);
    short8 b0 = *(const short8*)(bp);
    short8 b1 = *(const short8*)(bp + 512);
    short8 b2 = *(const short8*)(bp + 1024);
    short8 b3 = *(const short8*)(bp + 1536);
    bp += 2048;
    ai = MFMA(a, b0, ai); af = MFMA(a, b1, af);
    ag = MFMA(a, b2, ag); ao = MFMA(a, b3, ao);
  }
  #pragma unroll
  for (int r = 0; r < 16; ++r) {
    float si = sigm(ai[r]);
    float sf = sigm(af[r]);
    float tg = tanh_f(ag[r]);
    float so = sigm(ao[r]);
    float cn = sf * c_reg[r] + si * tg;
    c_reg[r] = cn;
    hnew[r] = so * tanh_f(cn);
  }
}

__device__ __forceinline__ void write_h16(short* hl, int lane, int wv, const float hnew[16]) {
  int arow = lane & 31, ahalf = lane >> 5;
  int col = (wv << 5) + arow;
  #pragma unroll
  for (int r = 0; r < 16; ++r) {
    int row = (r & 3) + ((r >> 2) << 3) + (ahalf << 2);
    hl[row * LROW + col] = (short)f2bf(hnew[r]);
  }
}

// ---------------- encoder: dbuf h -> ONE barrier per step (R6, known-good) ---
__global__ __launch_bounds__(1024) void lstm_encoder(
    const float* __restrict__ speed, const float* __restrict__ pos,
    const short* __restrict__ wpack,
    short* __restrict__ h_enc, float* __restrict__ c_enc)
{
  __shared__ short hl[2][NROW * LROW];
  int tid = threadIdx.x;
  int b = blockIdx.x;
  int xcd = b & 7, slot = b >> 3;
  int enc = xcd >> 2;               // XCDs 0-3: speed, 4-7: pos (L2 locality)
  int rg = slot * 4 + (xcd & 3);    // 0..127
  int r0 = rg * 32;
  const float* xin = enc ? pos : speed;
  const short* wm = wpack + (size_t)enc * WMAT_ELEMS;

  {
    short* hz = &hl[0][0];
    for (int i = tid; i < 2 * NROW * LROW; i += 1024) hz[i] = 0;
  }
  __syncthreads();
  if (tid < 64) hl[tid >> 5][(tid & 31) * LROW + 516] = (short)0x3F80;  // bias, both bufs
  if (tid < 128) {
    int r = tid >> 2, c = tid & 3;
    hl[0][r * LROW + 512 + c] = (short)f2bf(xin[(r0 + r) * 64 + c]);    // x_0
  }
  __syncthreads();

  int lane = tid & 63, wv = tid >> 6;   // wv in [0,16)
  float c_reg[16];
  #pragma unroll
  for (int r = 0; r < 16; ++r) c_reg[r] = 0.0f;
  float hnew[16];

  for (int t = 0; t < 16; ++t) {
    const short* cb = hl[t & 1];
    short* nb = &hl[(t + 1) & 1][0];
    lstm_step_mfma(cb, wm, lane, wv, c_reg, hnew);
    write_h16(nb, lane, wv, hnew);
    if (t < 15 && tid < 128) {
      int r = tid >> 2, c = tid & 3;
      nb[r * LROW + 512 + c] = (short)f2bf(xin[(r0 + r) * 64 + (t + 1) * 4 + c]);
    }
    __syncthreads();
  }

  // final h lives in hl[0] (t=15 wrote buf (15+1)&1 = 0)
  for (int i = tid; i < 32 * 512; i += 1024) {
    int r = i >> 9, k = i & 511;
    h_enc[((size_t)(enc * B_TOT + r0 + r) << 9) + k] = hl[0][r * LROW + k];
  }
  int arow = lane & 31, ahalf = lane >> 5;
  int col = (wv << 5) + arow;
  #pragma unroll
  for (int r = 0; r < 16; ++r) {
    int row = (r & 3) + ((r >> 2) << 3) + (ahalf << 2);
    c_enc[((size_t)(enc * B_TOT + r0 + row) << 9) + col] = c_reg[r];
  }
}

// ---------------- decoder: 1024 thr, dbuf h, heads hidden under next k-loop --
// Per step: [kt0..31 on h(t)] SB [kt32: x(t) aug] [act + write_h(t+1)] SA
//           [heads(t): read h(t+1), write out + x(t+1) into nb aug cols]
// No barrier after heads -> each wave rolls into kt0..31 of t+1; the heads'
// shuffle/VMEM latency overlaps other waves' MFMA. SB of step t+1 makes the
// x(t+1) aug writes visible before kt32 consumes them. 2 barriers/step.
__global__ __launch_bounds__(1024) void lstm_decoder(
    const float* __restrict__ speed, const float* __restrict__ pos,
    const short* __restrict__ wpack,
    const short* __restrict__ h_enc, const float* __restrict__ c_enc,
    const float* __restrict__ W_fs, const float* __restrict__ b_fs,
    const float* __restrict__ W_fc, const float* __restrict__ b_fc,
    const float* __restrict__ W_emb, const float* __restrict__ b_emb,
    float* __restrict__ out)
{
  __shared__ short hl[2][NROW * LROW];
  int tid = threadIdx.x;
  int b = blockIdx.x;
  int xcd = b & 7, slot = b >> 3;
  int chain = xcd >> 2;
  int rg = slot * 4 + (xcd & 3);
  int r0 = rg * 32;
  const short* wm = wpack + (size_t)(2 + chain) * WMAT_ELEMS;
  int lane = tid & 63, wv = tid >> 6;   // wv in [0,16)
  int arow = lane & 31, ahalf = lane >> 5;

  {
    short* hz = &hl[0][0];
    for (int i = tid; i < 2 * NROW * LROW; i += 1024) hz[i] = 0;
  }
  __syncthreads();
  // h(0) = h_se + h_pe into hl[0]
  for (int i = tid; i < 32 * 512; i += 1024) {
    int r = i >> 9, k = i & 511;
    float h0 = bf2f((unsigned short)h_enc[((size_t)(r0 + r) << 9) + k])
             + bf2f((unsigned short)h_enc[((size_t)(B_TOT + r0 + r) << 9) + k]);
    hl[0][r * LROW + k] = (short)f2bf(h0);
  }
  if (tid < 64) hl[tid >> 5][(tid & 31) * LROW + 516] = (short)0x3F80;  // bias, both bufs
  {
    const float* last = chain ? pos : speed;
    if (tid < 128) {
      int r = tid >> 2, c = tid & 3;
      hl[0][r * LROW + 512 + c] = (short)f2bf(last[(r0 + r) * 64 + 60 + c]); // x(0)
    }
  }

  float c_reg[16];
  {
    int col = (wv << 5) + arow;
    #pragma unroll
    for (int r = 0; r < 16; ++r) {
      int row = (r & 3) + ((r >> 2) << 3) + (ahalf << 2);
      size_t gi = ((size_t)(r0 + row) << 9) + col;
      c_reg[r] = c_enc[gi] + c_enc[gi + (((size_t)B_TOT) << 9)];
    }
  }
  __syncthreads();

  float hnew[16];
  for (int t = 0; t < T_DEC; ++t) {
    const short* cb = hl[t & 1];
    short* nb = &hl[(t + 1) & 1][0];
    const short* aptr = cb + arow * LROW + ahalf * 8;
    const short* bp = wm + (size_t)wv * (KT_N * 4 * 512) + (lane << 3);

    // ---- k-loop kt 0..31 (Wh·h, needs only h(t)) ----------------------------
    floatx16 ai = (floatx16)0.0f, af = (floatx16)0.0f,
             ag = (floatx16)0.0f, ao = (floatx16)0.0f;
    #pragma unroll 4
    for (int kt = 0; kt < 32; ++kt) {
      short8 a  = *(const short8*)(aptr + kt * 16);
      short8 b0 = *(const short8*)(bp);
      short8 b1 = *(const short8*)(bp + 512);
      short8 b2 = *(const short8*)(bp + 1024);
      short8 b3 = *(const short8*)(bp + 1536);
      bp += 2048;
      ai = MFMA(a, b0, ai); af = MFMA(a, b1, af);
      ag = MFMA(a, b2, ag); ao = MFMA(a, b3, ao);
    }
    __syncthreads();              // SB: x(t) aug writes (heads t-1) visible
    { // kt = 32: x cols + bias (aug)
      short8 a  = *(const short8*)(aptr + 512);
      short8 b0 = *(const short8*)(bp);
      short8 b1 = *(const short8*)(bp + 512);
      short8 b2 = *(const short8*)(bp + 1024);
      short8 b3 = *(const short8*)(bp + 1536);
      ai = MFMA(a, b0, ai); af = MFMA(a, b1, af);
      ag = MFMA(a, b2, ag); ao = MFMA(a, b3, ao);
    }

    // ---- activations + write h(t+1) -----------------------------------------
    #pragma unroll
    for (int r = 0; r < 16; ++r) {
      float si = sigm(ai[r]);
      float sf = sigm(af[r]);
      float tg = tanh_f(ag[r]);
      float so = sigm(ao[r]);
      float cn = sf * c_reg[r] + si * tg;
      c_reg[r] = cn;
      hnew[r] = so * tanh_f(cn);
    }
    write_h16(nb, lane, wv, hnew);
    __syncthreads();              // SA: h(t+1) complete in nb

    // ---- heads (hidden: no trailing barrier; waves roll into next k-loop) ---
    // wave wv -> rows [wv*2, wv*2+2); head weights from global (L1-resident).
    #pragma unroll 1
    for (int r = 0; r < 2; ++r) {
      int row = wv * 2 + r;
      const short8 hvs = *(const short8*)(nb + row * LROW + lane * 8);
      float hv[8];
      #pragma unroll
      for (int j = 0; j < 8; ++j) hv[j] = bf2f((unsigned short)hvs[j]);
      if (chain == 0) {
        float p0 = 0.f, p1 = 0.f, p2 = 0.f, p3 = 0.f;
        #pragma unroll
        for (int j = 0; j < 8; ++j) {
          p0 += hv[j] * W_fs[0 * 512 + lane * 8 + j];
          p1 += hv[j] * W_fs[1 * 512 + lane * 8 + j];
          p2 += hv[j] * W_fs[2 * 512 + lane * 8 + j];
          p3 += hv[j] * W_fs[3 * 512 + lane * 8 + j];
        }
        #pragma unroll
        for (int off = 32; off > 0; off >>= 1) {
          p0 += __shfl_xor(p0, off);
          p1 += __shfl_xor(p1, off);
          p2 += __shfl_xor(p2, off);
          p3 += __shfl_xor(p3, off);
        }
        float s0 = fminf(fmaxf(p0 + b_fs[0], -100.0f), 100.0f);
        float s1 = fminf(fmaxf(p1 + b_fs[1], -100.0f), 100.0f);
        float s2 = fminf(fmaxf(p2 + b_fs[2], -100.0f), 100.0f);
        float s3 = fminf(fmaxf(p3 + b_fs[3], -100.0f), 100.0f);
        if (lane < 4) {
          float v = (lane == 0) ? s0 : (lane == 1) ? s1 : (lane == 2) ? s2 : s3;
          out[(size_t)(r0 + row) * 128 + t * 4 + lane] = v;       // speed_outputs
          nb[row * LROW + 512 + lane] = (short)f2bf(v);           // x(t+1) feedback
        }
      } else {
        float p0 = 0.f, p1 = 0.f;
        #pragma unroll
        for (int j = 0; j < 8; ++j) {
          p0 += hv[j] * W_fc[0 * 512 + lane * 8 + j];
          p1 += hv[j] * W_fc[1 * 512 + lane * 8 + j];
        }
        #pragma unroll
        for (int off = 32; off > 0; off >>= 1) {
          p0 += __shfl_xor(p0, off);
          p1 += __shfl_xor(p1, off);
        }
        float it0 = fmaxf(p0 + b_fc[0], 0.0f);
        float it1 = fmaxf(p1 + b_fc[1], 0.0f);
        if (lane < 4) {
          float lp = fmaxf(W_emb[lane * 2] * it0 + W_emb[lane * 2 + 1] * it1 + b_emb[lane], 0.0f);
          nb[row * LROW + 512 + lane] = (short)f2bf(lp);          // x(t+1) feedback
        }
        if (t == T_DEC - 1 && lane < 2) {
          float m = fmaxf(it0, it1);
          float e0 = __expf(it0 - m), e1 = __expf(it1 - m);
          float v = ((lane == 0) ? e0 : e1) * rcpf(e0 + e1);
          out[(size_t)524288 + (size_t)(r0 + row) * 2 + lane] = v; // crossing
        }
      }
    }
    // no barrier here: next iteration's SB orders the aug writes.
  }
}

extern "C" void kernel_launch(void* const* d_in, const int* in_sizes, int n_in,
                              void* d_out, int out_size, void* d_ws, size_t ws_size,
                              hipStream_t stream)
{
  const float* speed    = (const float*)d_in[0];
  const float* pos      = (const float*)d_in[1];
  const float* enc_s_Wi = (const float*)d_in[2];
  const float* enc_s_Wh = (const float*)d_in[3];
  const float* enc_s_b  = (const float*)d_in[4];
  const float* enc_p_Wi = (const float*)d_in[5];
  const float* enc_p_Wh = (const float*)d_in[6];
  const float* enc_p_b  = (const float*)d_in[7];
  const float* dec_s_Wi = (const float*)d_in[8];
  const float* dec_s_Wh = (const float*)d_in[9];
  const float* dec_s_b  = (const float*)d_in[10];
  const float* dec_i_Wi = (const float*)d_in[11];
  const float* dec_i_Wh = (const float*)d_in[12];
  const float* dec_i_b  = (const float*)d_in[13];
  const float* W_fs     = (const float*)d_in[14];
  const float* b_fs     = (const float*)d_in[15];
  const float* W_fc     = (const float*)d_in[16];
  const float* b_fc     = (const float*)d_in[17];
  const float* W_emb    = (const float*)d_in[18];
  const float* b_emb    = (const float*)d_in[19];
  float* out = (float*)d_out;

  char* ws = (char*)d_ws;
  short* wpack = (short*)ws;                 // 4 x 2,162,688 B = 8,650,752 B
  short* h_enc = (short*)(ws + 8650752);     // 2 x 4096 x 512 bf16 = 8,388,608 B
  float* c_enc = (float*)(ws + 17039360);    // 2 x 4096 x 512 f32  = 16,777,216 B

  prep_weights<<<16896, 256, 0, stream>>>(
      enc_s_Wh, enc_s_Wi, enc_s_b,
      enc_p_Wh, enc_p_Wi, enc_p_b,
      dec_s_Wh, dec_s_Wi, dec_s_b,
      dec_i_Wh, dec_i_Wi, dec_i_b,
      wpack);
  lstm_encoder<<<256, 1024, 0, stream>>>(speed, pos, wpack, h_enc, c_enc);
  lstm_decoder<<<256, 1024, 0, stream>>>(speed, pos, wpack, h_enc, c_enc,
                                         W_fs, b_fs, W_fc, b_fc, W_emb, b_emb, out);
}